// Round 8
// baseline (1036.462 us; speedup 1.0000x reference)
//
#include <hip/hip_runtime.h>
#include <hip/hip_bf16.h>

// ---------------------------------------------------------------------------
// RecurrentBattleNet: 2-layer LSTM (B=512, T=256, IN=512, H=128) + FC head.
// Round 8: recurrence ew decoupled from MFMA layout via LDS gate round-trip.
// RB 16->4 (128 blocks / 128 CUs), each thread owns exactly one (row,hid)
// unit in phase B (1 ds_read_b128 + 1 float4 xp + one 5-transcendental
// update), vs 4 exec-masked units/lane before. 2 raw barriers/step.
// ---------------------------------------------------------------------------

#define BATCH 512
#define SEQT  256
#define INPUTD 512
#define HID   128
#define GATES 512   // 4*HID
#define RB    4     // batch rows per recurrence block

typedef __bf16 bf16_t;
typedef bf16_t bf16x4 __attribute__((ext_vector_type(4)));
typedef bf16_t bf16x8 __attribute__((ext_vector_type(8)));
typedef float  f32x4  __attribute__((ext_vector_type(4)));

__device__ __forceinline__ float sigm(float x) {
    return __builtin_amdgcn_rcpf(1.f + __expf(-x));
}
__device__ __forceinline__ float tanhfast(float x) {
    float xc = fminf(fmaxf(x, -15.f), 15.f);
    float e = __expf(2.f * xc);
    return (e - 1.f) * __builtin_amdgcn_rcpf(e + 1.f);
}

// ---------------------------------------------------------------------------
// fp32 -> bf16 conversion, vectorized (float4 in, bf16x4 out). n4 = n/4.
// ---------------------------------------------------------------------------
__global__ __launch_bounds__(256) void cvt_f32_bf16(
    const float* __restrict__ in, bf16_t* __restrict__ out, long n4)
{
    long i = (long)blockIdx.x * 256 + threadIdx.x;
    long stride = (long)gridDim.x * 256;
    for (; i < n4; i += stride) {
        float4 v = ((const float4*)in)[i];
        bf16x4 r;
        r[0] = (bf16_t)v.x; r[1] = (bf16_t)v.y;
        r[2] = (bf16_t)v.z; r[3] = (bf16_t)v.w;
        ((bf16x4*)out)[i] = r;
    }
}

// ---------------------------------------------------------------------------
// bf16 MFMA GEMM writing the xp4 layout consumed by lstm_rec_mfma:
//   xp4[b>>2][t][ (b&3)*128 + hid ][ gate ]   (float, innermost 4 = i,f,g,o)
// A-side: logical row m -> physical row (m>>tcs)*srcT + t0 + (m&tcmask).
// 128x128 tile, BK=32, 256 thr (4 waves 2x2), 16x16x32 MFMA.
// ---------------------------------------------------------------------------
__global__ __launch_bounds__(256) void gemm_mfma(
    const bf16_t* __restrict__ A, const bf16_t* __restrict__ W,
    const float* __restrict__ b1, const float* __restrict__ b2,
    float* __restrict__ out,
    int K, int tcs, int tcmask, int srcT, int t0)
{
    __shared__ bf16_t As[128 * 32];
    __shared__ bf16_t Bs[128 * 32];
    int tid = threadIdx.x;
    int l = tid & 63;
    int w = tid >> 6;
    int wm = w >> 1, wn = w & 1;
    int bn = blockIdx.x;
    int bm = blockIdx.y;
    int Tc = tcmask + 1;

    long aoff[2], boff[2];
    #pragma unroll
    for (int c = 0; c < 2; ++c) {
        int m = bm * 128 + (tid >> 2) + 64 * c;
        int xr = ((m >> tcs) * srcT) + t0 + (m & tcmask);
        aoff[c] = (long)xr * K + (tid & 3) * 8;
        int n = bn * 128 + (tid >> 2) + 64 * c;
        boff[c] = (long)n * K + (tid & 3) * 8;
    }

    f32x4 acc[4][4];
    #pragma unroll
    for (int i = 0; i < 4; ++i)
        #pragma unroll
        for (int j = 0; j < 4; ++j)
            acc[i][j] = (f32x4){0.f, 0.f, 0.f, 0.f};

    const int rbase = wm * 64 + (l & 15);
    const int cbase = wn * 64 + (l & 15);
    const int kfrag = (l >> 4) * 8;

    for (int kt = 0; kt < K; kt += 32) {
        __builtin_amdgcn_global_load_lds(
            (const __attribute__((address_space(1))) void*)(A + aoff[0] + kt),
            (__attribute__((address_space(3))) void*)(As + tid * 8), 16, 0, 0);
        __builtin_amdgcn_global_load_lds(
            (const __attribute__((address_space(1))) void*)(A + aoff[1] + kt),
            (__attribute__((address_space(3))) void*)(As + 2048 + tid * 8), 16, 0, 0);
        __builtin_amdgcn_global_load_lds(
            (const __attribute__((address_space(1))) void*)(W + boff[0] + kt),
            (__attribute__((address_space(3))) void*)(Bs + tid * 8), 16, 0, 0);
        __builtin_amdgcn_global_load_lds(
            (const __attribute__((address_space(1))) void*)(W + boff[1] + kt),
            (__attribute__((address_space(3))) void*)(Bs + 2048 + tid * 8), 16, 0, 0);
        __syncthreads();

        bf16x8 af[4], bfr[4];
        #pragma unroll
        for (int i = 0; i < 4; ++i)
            af[i] = *(const bf16x8*)(As + (rbase + i * 16) * 32 + kfrag);
        #pragma unroll
        for (int j = 0; j < 4; ++j)
            bfr[j] = *(const bf16x8*)(Bs + (cbase + j * 16) * 32 + kfrag);

        #pragma unroll
        for (int i = 0; i < 4; ++i)
            #pragma unroll
            for (int j = 0; j < 4; ++j)
                acc[i][j] = __builtin_amdgcn_mfma_f32_16x16x32_bf16(
                    af[i], bfr[j], acc[i][j], 0, 0, 0);
        __syncthreads();
    }

    // epilogue: write xp4 layout (C row = (l>>4)*4 + r, col = l&15)
    #pragma unroll
    for (int i = 0; i < 4; ++i) {
        int m0 = bm * 128 + wm * 64 + i * 16 + (l >> 4) * 4;
        #pragma unroll
        for (int j = 0; j < 4; ++j) {
            int n = bn * 128 + wn * 64 + j * 16 + (l & 15);
            float bb = b1[n] + b2[n];
            int g = n >> 7;
            int hid = n & 127;
            #pragma unroll
            for (int r = 0; r < 4; ++r) {
                int m = m0 + r;
                int b = m >> tcs;
                int t = m & tcmask;
                int br = b >> 2, brow = b & 3;
                out[((((long)br * Tc + t) * 512) + brow * 128 + hid) * 4 + g] =
                    acc[i][j][r] + bb;
            }
        }
    }
}

// ---------------------------------------------------------------------------
// MFMA LSTM recurrence, RB=4 rows/block, 128 blocks. 8 waves; wave w owns
// gate cols {g*128 + w*16..+16}. Phase A: MFMA gates -> g_lds (packed
// [idx=row*128+hid][4gates], XOR-swizzled). Phase B: thread tid owns unit
// (row=tid>>7, hid=tid&127): 1 ds_read_b128 gates + float4 xp + gate math,
// h -> h_lds (single buffer) + hseq. Raw barriers (lgkmcnt only).
// ---------------------------------------------------------------------------
#define REC_STEP(X)                                                            \
    {                                                                          \
        f32x4 acc[4];                                                          \
        _Pragma("unroll")                                                      \
        for (int g = 0; g < 4; ++g) acc[g] = (f32x4){0.f, 0.f, 0.f, 0.f};      \
        _Pragma("unroll")                                                      \
        for (int ks = 0; ks < 4; ++ks) {                                       \
            int ba = (col * 256 + ks * 64 + lgroup * 16) ^ ((col & 7) << 4);   \
            bf16x8 a = *(const bf16x8*)((const char*)h_lds + ba);              \
            _Pragma("unroll")                                                  \
            for (int g = 0; g < 4; ++g)                                        \
                acc[g] = __builtin_amdgcn_mfma_f32_16x16x32_bf16(              \
                    a, __builtin_bit_cast(bf16x8, wreg[g][ks]), acc[g],        \
                    0, 0, 0);                                                  \
        }                                                                      \
        _Pragma("unroll")                                                      \
        for (int r = 0; r < 4; ++r) {                                          \
            int row = lgroup * 4 + r;                                          \
            f32x4 v;                                                           \
            v[0] = acc[0][r]; v[1] = acc[1][r];                                \
            v[2] = acc[2][r]; v[3] = acc[3][r];                                \
            int ba = (row * 2048 + coff * 16) ^ ((row & 7) << 4)               \
                     ^ ((row & 8) << 3);                                       \
            *(f32x4*)((char*)g_lds + ba) = v;                                  \
        }                                                                      \
        asm volatile("s_waitcnt lgkmcnt(0)" ::: "memory");                     \
        __builtin_amdgcn_s_barrier();                                          \
        __builtin_amdgcn_sched_barrier(0);                                     \
        f32x4 gv = *(const f32x4*)((const char*)g_lds + grd);                  \
        float zi = gv[0] + X.x;                                                \
        float zf = gv[1] + X.y;                                                \
        float zg = gv[2] + X.z;                                                \
        float zo = gv[3] + X.w;                                                \
        c = sigm(zf) * c + sigm(zi) * tanhfast(zg);                            \
        h = sigm(zo) * tanhfast(c);                                            \
        *(bf16_t*)((char*)h_lds + hba) = (bf16_t)h;                            \
        if (hq) hq[(long)t * HID] = (bf16_t)h;                                 \
        if (t + 2 < Tc) X = xpt[(long)(t + 2) * 512];                          \
        asm volatile("s_waitcnt lgkmcnt(0)" ::: "memory");                     \
        __builtin_amdgcn_s_barrier();                                          \
        __builtin_amdgcn_sched_barrier(0);                                     \
    }

__global__ __launch_bounds__(512, 2) void lstm_rec_mfma(
    const float* __restrict__ xp4,   // [B/4][Tc][512][4] float
    const bf16_t* __restrict__ Whh,  // [512,128] bf16
    bf16_t* __restrict__ hseq,       // [B, Tc, 128] bf16 or nullptr
    float* __restrict__ hst, float* __restrict__ cst,  // [B,128]
    int Tc, int first)
{
    __shared__ __align__(16) bf16_t h_lds[16 * HID];       // 4 KB, swizzled
    __shared__ __align__(16) float  g_lds[16 * HID * 4];   // 32 KB
    int tid = threadIdx.x;
    int l = tid & 63;
    int w = tid >> 6;                 // wave 0..7
    int r0 = blockIdx.x * RB;

    int col = l & 15;                 // A-row for MFMA frags / within-tile col
    int lgroup = l >> 4;              // 0..3
    int coff = w * 16 + col;          // owned gate-col (0..127) per gate
    int kreg = lgroup * 8;            // A/B fragment k offset

    // persistent weight fragments (64 VGPR/lane)
    f32x4 wreg[4][4];
    #pragma unroll
    for (int g = 0; g < 4; ++g)
        #pragma unroll
        for (int ks = 0; ks < 4; ++ks)
            wreg[g][ks] = *(const f32x4*)(Whh + (g * 128 + coff) * HID + ks * 32 + kreg);
    #pragma unroll
    for (int g = 0; g < 4; ++g)
        #pragma unroll
        for (int ks = 0; ks < 4; ++ks)
            asm volatile("" : "+v"(wreg[g][ks]));

    // elementwise identity: one (row,hid) unit per thread
    int erow = tid >> 7;              // 0..3
    int ehid = tid & 127;
    const int hba = (erow * 256 + ehid * 2) ^ ((erow & 7) << 4);
    const int grd = (tid * 16) ^ (erow << 4);  // g_lds read addr (row<4)
    float c = first ? 0.f : cst[(r0 + erow) * HID + ehid];
    float h = first ? 0.f : hst[(r0 + erow) * HID + ehid];
    bf16_t* hq = hseq ? hseq + ((long)(r0 + erow) * Tc) * HID + ehid : nullptr;

    // zero h_lds (rows 4-15 stay zero forever), then stage h rows 0-3
    ((float2*)h_lds)[tid] = make_float2(0.f, 0.f);
    __syncthreads();
    *(bf16_t*)((char*)h_lds + hba) = (bf16_t)h;
    __syncthreads();

    // per-thread xp stream (float4 = i,f,g,o for this unit), depth-2 prefetch
    const float4* xpt = (const float4*)xp4 + (long)blockIdx.x * Tc * 512 + tid;
    float4 xA = xpt[0];
    float4 xB = (Tc > 1) ? xpt[512] : make_float4(0.f, 0.f, 0.f, 0.f);

    for (int tt = 0; tt < Tc; tt += 2) {
        {
            int t = tt;
            REC_STEP(xA)
        }
        {
            int t = tt + 1;
            REC_STEP(xB)
        }
    }

    hst[(r0 + erow) * HID + ehid] = h;
    cst[(r0 + erow) * HID + ehid] = c;
}

// ---------------------------------------------------------------------------
// FC head + softmax + state copy-out. One block per batch row, 128 threads.
// out layout: probs [512*10] | h_n [2*512*128] | c_n [2*512*128]
// ---------------------------------------------------------------------------
__global__ __launch_bounds__(128) void fc_head(
    const float* __restrict__ h0st, const float* __restrict__ c0st,
    const float* __restrict__ h1st, const float* __restrict__ c1st,
    const float* __restrict__ fc1w, const float* __restrict__ fc1b,
    const float* __restrict__ fc2w, const float* __restrict__ fc2b,
    float* __restrict__ out)
{
    __shared__ float h1_s[HID];
    __shared__ float hid_s[64];
    __shared__ float log_s[10];
    int t = threadIdx.x;
    int b = blockIdx.x;

    h1_s[t] = h1st[b * HID + t];
    __syncthreads();

    if (t < 64) {
        float a = fc1b[t];
        const float* wrow = fc1w + t * HID;
        #pragma unroll 4
        for (int k = 0; k < HID; ++k) a = fmaf(wrow[k], h1_s[k], a);
        hid_s[t] = fmaxf(a, 0.f);
    }
    __syncthreads();

    if (t < 10) {
        float a = fc2b[t];
        const float* wrow = fc2w + t * 64;
        #pragma unroll 4
        for (int k = 0; k < 64; ++k) a = fmaf(wrow[k], hid_s[k], a);
        log_s[t] = a;
    }
    __syncthreads();

    if (t == 0) {
        float m = log_s[0];
        #pragma unroll
        for (int j = 1; j < 10; ++j) m = fmaxf(m, log_s[j]);
        float e[10];
        float s = 0.f;
        #pragma unroll
        for (int j = 0; j < 10; ++j) { e[j] = __expf(log_s[j] - m); s += e[j]; }
        float inv = __builtin_amdgcn_rcpf(s);
        #pragma unroll
        for (int j = 0; j < 10; ++j) out[b * 10 + j] = e[j] * inv;
    }

    float* hn = out + BATCH * 10;
    float* cn = hn + 2 * BATCH * HID;
    hn[b * HID + t] = h0st[b * HID + t];
    hn[BATCH * HID + b * HID + t] = h1_s[t];
    cn[b * HID + t] = c0st[b * HID + t];
    cn[BATCH * HID + b * HID + t] = c1st[b * HID + t];
}

// ---------------------------------------------------------------------------
extern "C" void kernel_launch(void* const* d_in, const int* in_sizes, int n_in,
                              void* d_out, int out_size, void* d_ws, size_t ws_size,
                              hipStream_t stream) {
    const float* x    = (const float*)d_in[0];
    const float* Wih0 = (const float*)d_in[1];
    const float* Whh0 = (const float*)d_in[2];
    const float* bih0 = (const float*)d_in[3];
    const float* bhh0 = (const float*)d_in[4];
    const float* Wih1 = (const float*)d_in[5];
    const float* Whh1 = (const float*)d_in[6];
    const float* bih1 = (const float*)d_in[7];
    const float* bhh1 = (const float*)d_in[8];
    const float* fc1w = (const float*)d_in[9];
    const float* fc1b = (const float*)d_in[10];
    const float* fc2w = (const float*)d_in[11];
    const float* fc2b = (const float*)d_in[12];
    float* out = (float*)d_out;

    int Tc = SEQT;
    while (Tc > 1) {
        size_t need = (size_t)BATCH * Tc * GATES * 4       // xp4
                    + (size_t)BATCH * Tc * HID * 2         // h0b
                    + (size_t)BATCH * SEQT * INPUTD * 2    // xb
                    + ((size_t)GATES * INPUTD + 3 * (size_t)GATES * HID) * 2
                    + 4 * (size_t)BATCH * HID * 4 + 256;
        if (need <= ws_size) break;
        Tc >>= 1;
    }
    int tcs = __builtin_ctz((unsigned)Tc);

    float*  xp   = (float*)d_ws;
    bf16_t* h0b  = (bf16_t*)(xp + (size_t)BATCH * Tc * GATES);
    bf16_t* xb   = h0b + (size_t)BATCH * Tc * HID;
    bf16_t* wb0  = xb + (size_t)BATCH * SEQT * INPUTD;
    bf16_t* wb1  = wb0 + (size_t)GATES * INPUTD;
    bf16_t* wh0b = wb1 + (size_t)GATES * HID;
    bf16_t* wh1b = wh0b + (size_t)GATES * HID;
    float*  h0st = (float*)(wh1b + (size_t)GATES * HID);
    float*  c0st = h0st + (size_t)BATCH * HID;
    float*  h1st = c0st + (size_t)BATCH * HID;
    float*  c1st = h1st + (size_t)BATCH * HID;

    cvt_f32_bf16<<<2048, 256, 0, stream>>>(x, xb, (long)BATCH * SEQT * INPUTD / 4);
    cvt_f32_bf16<<<256, 256, 0, stream>>>(Wih0, wb0, (long)GATES * INPUTD / 4);
    cvt_f32_bf16<<<64, 256, 0, stream>>>(Wih1, wb1, (long)GATES * HID / 4);
    cvt_f32_bf16<<<64, 256, 0, stream>>>(Whh0, wh0b, (long)GATES * HID / 4);
    cvt_f32_bf16<<<64, 256, 0, stream>>>(Whh1, wh1b, (long)GATES * HID / 4);

    int nchunk = SEQT / Tc;
    dim3 gemm_grid(GATES / 128, (BATCH * Tc) / 128);

    for (int ci = 0; ci < nchunk; ++ci) {
        int t0 = ci * Tc;
        gemm_mfma<<<gemm_grid, 256, 0, stream>>>(
            xb, wb0, bih0, bhh0, xp, INPUTD, tcs, Tc - 1, SEQT, t0);
        lstm_rec_mfma<<<BATCH / RB, 512, 0, stream>>>(
            xp, wh0b, h0b, h0st, c0st, Tc, ci == 0);
        gemm_mfma<<<gemm_grid, 256, 0, stream>>>(
            h0b, wb1, bih1, bhh1, xp, HID, tcs, Tc - 1, Tc, 0);
        lstm_rec_mfma<<<BATCH / RB, 512, 0, stream>>>(
            xp, wh1b, nullptr, h1st, c1st, Tc, ci == 0);
    }

    fc_head<<<BATCH, 128, 0, stream>>>(
        h0st, c0st, h1st, c1st, fc1w, fc1b, fc2w, fc2b, out);
}

// Round 9
// 746.665 us; speedup vs baseline: 1.3881x; 1.3881x over previous
//
#include <hip/hip_runtime.h>
#include <hip/hip_bf16.h>

// ---------------------------------------------------------------------------
// RecurrentBattleNet: 2-layer LSTM (B=512, T=256, IN=512, H=128) + FC head.
// Round 9: fix R8's GEMM write-amplification — xp layout gate-major
// (xp4[br][t][gate][brow*128+hid]) so GEMM epilogue writes 64B-contiguous
// runs again (R8's [unit][gate] interleave scattered 4B dwords at 16B
// stride: WRITE_SIZE 1.07GB for 268MB of data, gemm 100->328us).
// Rec reads its unit's 4 gates as 4 coalesced dwords (stride 2KB).
// ---------------------------------------------------------------------------

#define BATCH 512
#define SEQT  256
#define INPUTD 512
#define HID   128
#define GATES 512   // 4*HID
#define RB    4     // batch rows per recurrence block

typedef __bf16 bf16_t;
typedef bf16_t bf16x4 __attribute__((ext_vector_type(4)));
typedef bf16_t bf16x8 __attribute__((ext_vector_type(8)));
typedef float  f32x4  __attribute__((ext_vector_type(4)));

__device__ __forceinline__ float sigm(float x) {
    return __builtin_amdgcn_rcpf(1.f + __expf(-x));
}
__device__ __forceinline__ float tanhfast(float x) {
    float xc = fminf(fmaxf(x, -15.f), 15.f);
    float e = __expf(2.f * xc);
    return (e - 1.f) * __builtin_amdgcn_rcpf(e + 1.f);
}

// ---------------------------------------------------------------------------
// fp32 -> bf16 conversion, vectorized (float4 in, bf16x4 out). n4 = n/4.
// ---------------------------------------------------------------------------
__global__ __launch_bounds__(256) void cvt_f32_bf16(
    const float* __restrict__ in, bf16_t* __restrict__ out, long n4)
{
    long i = (long)blockIdx.x * 256 + threadIdx.x;
    long stride = (long)gridDim.x * 256;
    for (; i < n4; i += stride) {
        float4 v = ((const float4*)in)[i];
        bf16x4 r;
        r[0] = (bf16_t)v.x; r[1] = (bf16_t)v.y;
        r[2] = (bf16_t)v.z; r[3] = (bf16_t)v.w;
        ((bf16x4*)out)[i] = r;
    }
}

// ---------------------------------------------------------------------------
// bf16 MFMA GEMM writing the gate-major xp layout consumed by lstm_rec_mfma:
//   xp4[b>>2][t][gate][(b&3)*128 + hid]   (float)
// A-side: logical row m -> physical row (m>>tcs)*srcT + t0 + (m&tcmask).
// 128x128 tile, BK=32, 256 thr (4 waves 2x2), 16x16x32 MFMA. Block bn
// covers gate g=bn exactly (n>>7 == bn), so epilogue runs are contiguous.
// ---------------------------------------------------------------------------
__global__ __launch_bounds__(256) void gemm_mfma(
    const bf16_t* __restrict__ A, const bf16_t* __restrict__ W,
    const float* __restrict__ b1, const float* __restrict__ b2,
    float* __restrict__ out,
    int K, int tcs, int tcmask, int srcT, int t0)
{
    __shared__ bf16_t As[128 * 32];
    __shared__ bf16_t Bs[128 * 32];
    int tid = threadIdx.x;
    int l = tid & 63;
    int w = tid >> 6;
    int wm = w >> 1, wn = w & 1;
    int bn = blockIdx.x;
    int bm = blockIdx.y;
    int Tc = tcmask + 1;

    long aoff[2], boff[2];
    #pragma unroll
    for (int c = 0; c < 2; ++c) {
        int m = bm * 128 + (tid >> 2) + 64 * c;
        int xr = ((m >> tcs) * srcT) + t0 + (m & tcmask);
        aoff[c] = (long)xr * K + (tid & 3) * 8;
        int n = bn * 128 + (tid >> 2) + 64 * c;
        boff[c] = (long)n * K + (tid & 3) * 8;
    }

    f32x4 acc[4][4];
    #pragma unroll
    for (int i = 0; i < 4; ++i)
        #pragma unroll
        for (int j = 0; j < 4; ++j)
            acc[i][j] = (f32x4){0.f, 0.f, 0.f, 0.f};

    const int rbase = wm * 64 + (l & 15);
    const int cbase = wn * 64 + (l & 15);
    const int kfrag = (l >> 4) * 8;

    for (int kt = 0; kt < K; kt += 32) {
        __builtin_amdgcn_global_load_lds(
            (const __attribute__((address_space(1))) void*)(A + aoff[0] + kt),
            (__attribute__((address_space(3))) void*)(As + tid * 8), 16, 0, 0);
        __builtin_amdgcn_global_load_lds(
            (const __attribute__((address_space(1))) void*)(A + aoff[1] + kt),
            (__attribute__((address_space(3))) void*)(As + 2048 + tid * 8), 16, 0, 0);
        __builtin_amdgcn_global_load_lds(
            (const __attribute__((address_space(1))) void*)(W + boff[0] + kt),
            (__attribute__((address_space(3))) void*)(Bs + tid * 8), 16, 0, 0);
        __builtin_amdgcn_global_load_lds(
            (const __attribute__((address_space(1))) void*)(W + boff[1] + kt),
            (__attribute__((address_space(3))) void*)(Bs + 2048 + tid * 8), 16, 0, 0);
        __syncthreads();

        bf16x8 af[4], bfr[4];
        #pragma unroll
        for (int i = 0; i < 4; ++i)
            af[i] = *(const bf16x8*)(As + (rbase + i * 16) * 32 + kfrag);
        #pragma unroll
        for (int j = 0; j < 4; ++j)
            bfr[j] = *(const bf16x8*)(Bs + (cbase + j * 16) * 32 + kfrag);

        #pragma unroll
        for (int i = 0; i < 4; ++i)
            #pragma unroll
            for (int j = 0; j < 4; ++j)
                acc[i][j] = __builtin_amdgcn_mfma_f32_16x16x32_bf16(
                    af[i], bfr[j], acc[i][j], 0, 0, 0);
        __syncthreads();
    }

    // epilogue: write gate-major xp4 (C row = (l>>4)*4 + r, col = l&15)
    #pragma unroll
    for (int i = 0; i < 4; ++i) {
        int m0 = bm * 128 + wm * 64 + i * 16 + (l >> 4) * 4;
        #pragma unroll
        for (int j = 0; j < 4; ++j) {
            int n = bn * 128 + wn * 64 + j * 16 + (l & 15);
            float bb = b1[n] + b2[n];
            int hid = n & 127;          // g == bn
            #pragma unroll
            for (int r = 0; r < 4; ++r) {
                int m = m0 + r;
                int b = m >> tcs;
                int t = m & tcmask;
                int br = b >> 2, brow = b & 3;
                out[(((long)br * Tc + t) * 4 + bn) * 512 + brow * 128 + hid] =
                    acc[i][j][r] + bb;
            }
        }
    }
}

// ---------------------------------------------------------------------------
// MFMA LSTM recurrence, RB=4 rows/block, 128 blocks. 8 waves; wave w owns
// gate cols {g*128 + w*16..+16}. Phase A: MFMA gates -> g_lds (packed
// [idx=row*128+hid][4gates], XOR-swizzled). Phase B: thread tid owns unit
// (row=tid>>7, hid=tid&127): 1 ds_read_b128 gates + 4 xp dwords + gate
// math, h -> h_lds (single buffer) + hseq. Raw barriers (lgkmcnt only).
// ---------------------------------------------------------------------------
#define REC_STEP(X)                                                            \
    {                                                                          \
        f32x4 acc[4];                                                          \
        _Pragma("unroll")                                                      \
        for (int g = 0; g < 4; ++g) acc[g] = (f32x4){0.f, 0.f, 0.f, 0.f};      \
        _Pragma("unroll")                                                      \
        for (int ks = 0; ks < 4; ++ks) {                                       \
            int ba = (col * 256 + ks * 64 + lgroup * 16) ^ ((col & 7) << 4);   \
            bf16x8 a = *(const bf16x8*)((const char*)h_lds + ba);              \
            _Pragma("unroll")                                                  \
            for (int g = 0; g < 4; ++g)                                        \
                acc[g] = __builtin_amdgcn_mfma_f32_16x16x32_bf16(              \
                    a, __builtin_bit_cast(bf16x8, wreg[g][ks]), acc[g],        \
                    0, 0, 0);                                                  \
        }                                                                      \
        _Pragma("unroll")                                                      \
        for (int r = 0; r < 4; ++r) {                                          \
            int row = lgroup * 4 + r;                                          \
            f32x4 v;                                                           \
            v[0] = acc[0][r]; v[1] = acc[1][r];                                \
            v[2] = acc[2][r]; v[3] = acc[3][r];                                \
            int ba = (row * 2048 + coff * 16) ^ ((row & 7) << 4)               \
                     ^ ((row & 8) << 3);                                       \
            *(f32x4*)((char*)g_lds + ba) = v;                                  \
        }                                                                      \
        asm volatile("s_waitcnt lgkmcnt(0)" ::: "memory");                     \
        __builtin_amdgcn_s_barrier();                                          \
        __builtin_amdgcn_sched_barrier(0);                                     \
        f32x4 gv = *(const f32x4*)((const char*)g_lds + grd);                  \
        float zi = gv[0] + X.x;                                                \
        float zf = gv[1] + X.y;                                                \
        float zg = gv[2] + X.z;                                                \
        float zo = gv[3] + X.w;                                                \
        c = sigm(zf) * c + sigm(zi) * tanhfast(zg);                            \
        h = sigm(zo) * tanhfast(c);                                            \
        *(bf16_t*)((char*)h_lds + hba) = (bf16_t)h;                            \
        if (hq) hq[(long)t * HID] = (bf16_t)h;                                 \
        if (t + 2 < Tc) {                                                      \
            X.x = xpt[(long)(t + 2) * 2048];                                   \
            X.y = xpt[(long)(t + 2) * 2048 + 512];                             \
            X.z = xpt[(long)(t + 2) * 2048 + 1024];                            \
            X.w = xpt[(long)(t + 2) * 2048 + 1536];                            \
        }                                                                      \
        asm volatile("s_waitcnt lgkmcnt(0)" ::: "memory");                     \
        __builtin_amdgcn_s_barrier();                                          \
        __builtin_amdgcn_sched_barrier(0);                                     \
    }

__global__ __launch_bounds__(512, 2) void lstm_rec_mfma(
    const float* __restrict__ xp4,   // [B/4][Tc][4][512] float (gate-major)
    const bf16_t* __restrict__ Whh,  // [512,128] bf16
    bf16_t* __restrict__ hseq,       // [B, Tc, 128] bf16 or nullptr
    float* __restrict__ hst, float* __restrict__ cst,  // [B,128]
    int Tc, int first)
{
    __shared__ __align__(16) bf16_t h_lds[16 * HID];       // 4 KB, swizzled
    __shared__ __align__(16) float  g_lds[16 * HID * 4];   // 32 KB
    int tid = threadIdx.x;
    int l = tid & 63;
    int w = tid >> 6;                 // wave 0..7
    int r0 = blockIdx.x * RB;

    int col = l & 15;                 // A-row for MFMA frags / within-tile col
    int lgroup = l >> 4;              // 0..3
    int coff = w * 16 + col;          // owned gate-col (0..127) per gate
    int kreg = lgroup * 8;            // A/B fragment k offset

    // persistent weight fragments (64 VGPR/lane)
    f32x4 wreg[4][4];
    #pragma unroll
    for (int g = 0; g < 4; ++g)
        #pragma unroll
        for (int ks = 0; ks < 4; ++ks)
            wreg[g][ks] = *(const f32x4*)(Whh + (g * 128 + coff) * HID + ks * 32 + kreg);
    #pragma unroll
    for (int g = 0; g < 4; ++g)
        #pragma unroll
        for (int ks = 0; ks < 4; ++ks)
            asm volatile("" : "+v"(wreg[g][ks]));

    // elementwise identity: one (row,hid) unit per thread
    int erow = tid >> 7;              // 0..3
    int ehid = tid & 127;
    const int hba = (erow * 256 + ehid * 2) ^ ((erow & 7) << 4);
    const int grd = (tid * 16) ^ (erow << 4);  // g_lds read addr (row<4)
    float c = first ? 0.f : cst[(r0 + erow) * HID + ehid];
    float h = first ? 0.f : hst[(r0 + erow) * HID + ehid];
    bf16_t* hq = hseq ? hseq + ((long)(r0 + erow) * Tc) * HID + ehid : nullptr;

    // zero h_lds (rows 4-15 stay zero forever), then stage h rows 0-3
    ((float2*)h_lds)[tid] = make_float2(0.f, 0.f);
    __syncthreads();
    *(bf16_t*)((char*)h_lds + hba) = (bf16_t)h;
    __syncthreads();

    // per-thread xp stream: unit tid reads 4 gates at g*512 + tid per step
    const float* xpt = xp4 + (long)blockIdx.x * Tc * 2048 + tid;
    float4 xA, xB;
    xA.x = xpt[0];    xA.y = xpt[512];
    xA.z = xpt[1024]; xA.w = xpt[1536];
    if (Tc > 1) {
        xB.x = xpt[2048];        xB.y = xpt[2048 + 512];
        xB.z = xpt[2048 + 1024]; xB.w = xpt[2048 + 1536];
    } else {
        xB = make_float4(0.f, 0.f, 0.f, 0.f);
    }

    for (int tt = 0; tt < Tc; tt += 2) {
        {
            int t = tt;
            REC_STEP(xA)
        }
        {
            int t = tt + 1;
            REC_STEP(xB)
        }
    }

    hst[(r0 + erow) * HID + ehid] = h;
    cst[(r0 + erow) * HID + ehid] = c;
}

// ---------------------------------------------------------------------------
// FC head + softmax + state copy-out. One block per batch row, 128 threads.
// out layout: probs [512*10] | h_n [2*512*128] | c_n [2*512*128]
// ---------------------------------------------------------------------------
__global__ __launch_bounds__(128) void fc_head(
    const float* __restrict__ h0st, const float* __restrict__ c0st,
    const float* __restrict__ h1st, const float* __restrict__ c1st,
    const float* __restrict__ fc1w, const float* __restrict__ fc1b,
    const float* __restrict__ fc2w, const float* __restrict__ fc2b,
    float* __restrict__ out)
{
    __shared__ float h1_s[HID];
    __shared__ float hid_s[64];
    __shared__ float log_s[10];
    int t = threadIdx.x;
    int b = blockIdx.x;

    h1_s[t] = h1st[b * HID + t];
    __syncthreads();

    if (t < 64) {
        float a = fc1b[t];
        const float* wrow = fc1w + t * HID;
        #pragma unroll 4
        for (int k = 0; k < HID; ++k) a = fmaf(wrow[k], h1_s[k], a);
        hid_s[t] = fmaxf(a, 0.f);
    }
    __syncthreads();

    if (t < 10) {
        float a = fc2b[t];
        const float* wrow = fc2w + t * 64;
        #pragma unroll 4
        for (int k = 0; k < 64; ++k) a = fmaf(wrow[k], hid_s[k], a);
        log_s[t] = a;
    }
    __syncthreads();

    if (t == 0) {
        float m = log_s[0];
        #pragma unroll
        for (int j = 1; j < 10; ++j) m = fmaxf(m, log_s[j]);
        float e[10];
        float s = 0.f;
        #pragma unroll
        for (int j = 0; j < 10; ++j) { e[j] = __expf(log_s[j] - m); s += e[j]; }
        float inv = __builtin_amdgcn_rcpf(s);
        #pragma unroll
        for (int j = 0; j < 10; ++j) out[b * 10 + j] = e[j] * inv;
    }

    float* hn = out + BATCH * 10;
    float* cn = hn + 2 * BATCH * HID;
    hn[b * HID + t] = h0st[b * HID + t];
    hn[BATCH * HID + b * HID + t] = h1_s[t];
    cn[b * HID + t] = c0st[b * HID + t];
    cn[BATCH * HID + b * HID + t] = c1st[b * HID + t];
}

// ---------------------------------------------------------------------------
extern "C" void kernel_launch(void* const* d_in, const int* in_sizes, int n_in,
                              void* d_out, int out_size, void* d_ws, size_t ws_size,
                              hipStream_t stream) {
    const float* x    = (const float*)d_in[0];
    const float* Wih0 = (const float*)d_in[1];
    const float* Whh0 = (const float*)d_in[2];
    const float* bih0 = (const float*)d_in[3];
    const float* bhh0 = (const float*)d_in[4];
    const float* Wih1 = (const float*)d_in[5];
    const float* Whh1 = (const float*)d_in[6];
    const float* bih1 = (const float*)d_in[7];
    const float* bhh1 = (const float*)d_in[8];
    const float* fc1w = (const float*)d_in[9];
    const float* fc1b = (const float*)d_in[10];
    const float* fc2w = (const float*)d_in[11];
    const float* fc2b = (const float*)d_in[12];
    float* out = (float*)d_out;

    int Tc = SEQT;
    while (Tc > 1) {
        size_t need = (size_t)BATCH * Tc * GATES * 4       // xp4
                    + (size_t)BATCH * Tc * HID * 2         // h0b
                    + (size_t)BATCH * SEQT * INPUTD * 2    // xb
                    + ((size_t)GATES * INPUTD + 3 * (size_t)GATES * HID) * 2
                    + 4 * (size_t)BATCH * HID * 4 + 256;
        if (need <= ws_size) break;
        Tc >>= 1;
    }
    int tcs = __builtin_ctz((unsigned)Tc);

    float*  xp   = (float*)d_ws;
    bf16_t* h0b  = (bf16_t*)(xp + (size_t)BATCH * Tc * GATES);
    bf16_t* xb   = h0b + (size_t)BATCH * Tc * HID;
    bf16_t* wb0  = xb + (size_t)BATCH * SEQT * INPUTD;
    bf16_t* wb1  = wb0 + (size_t)GATES * INPUTD;
    bf16_t* wh0b = wb1 + (size_t)GATES * HID;
    bf16_t* wh1b = wh0b + (size_t)GATES * HID;
    float*  h0st = (float*)(wh1b + (size_t)GATES * HID);
    float*  c0st = h0st + (size_t)BATCH * HID;
    float*  h1st = c0st + (size_t)BATCH * HID;
    float*  c1st = h1st + (size_t)BATCH * HID;

    cvt_f32_bf16<<<2048, 256, 0, stream>>>(x, xb, (long)BATCH * SEQT * INPUTD / 4);
    cvt_f32_bf16<<<256, 256, 0, stream>>>(Wih0, wb0, (long)GATES * INPUTD / 4);
    cvt_f32_bf16<<<64, 256, 0, stream>>>(Wih1, wb1, (long)GATES * HID / 4);
    cvt_f32_bf16<<<64, 256, 0, stream>>>(Whh0, wh0b, (long)GATES * HID / 4);
    cvt_f32_bf16<<<64, 256, 0, stream>>>(Whh1, wh1b, (long)GATES * HID / 4);

    int nchunk = SEQT / Tc;
    dim3 gemm_grid(GATES / 128, (BATCH * Tc) / 128);

    for (int ci = 0; ci < nchunk; ++ci) {
        int t0 = ci * Tc;
        gemm_mfma<<<gemm_grid, 256, 0, stream>>>(
            xb, wb0, bih0, bhh0, xp, INPUTD, tcs, Tc - 1, SEQT, t0);
        lstm_rec_mfma<<<BATCH / RB, 512, 0, stream>>>(
            xp, wh0b, h0b, h0st, c0st, Tc, ci == 0);
        gemm_mfma<<<gemm_grid, 256, 0, stream>>>(
            h0b, wb1, bih1, bhh1, xp, HID, tcs, Tc - 1, Tc, 0);
        lstm_rec_mfma<<<BATCH / RB, 512, 0, stream>>>(
            xp, wh1b, nullptr, h1st, c1st, Tc, ci == 0);
    }

    fc_head<<<BATCH, 128, 0, stream>>>(
        h0st, c0st, h1st, c1st, fc1w, fc1b, fc2w, fc2b, out);
}